// Round 7
// baseline (171.837 us; speedup 1.0000x reference)
//
#include <hip/hip_runtime.h>
#include <stdint.h>

#define DMAX 80
#define BLK  256
#define WPB  4                 // waves per block
#define RPW  4                 // row-rounds per block
#define RPB  (WPB * RPW)       // 16 rows per block
#define CW   3584              // columns per chunk (multiple of 4)

typedef float f32x4 __attribute__((ext_vector_type(4)));

// LDS index padding to break stride-4 bank conflicts on table reads
__device__ __forceinline__ int swz(int q) { return q + (q >> 5); }

// ---------------------------------------------------------------------------
// Setup: mask detect + compact idx; build pairtab (u16 i|j<<8) and coltab
// (u32 p|k<<16, column c = pps[p]*xls[k]); sentinel-pad coltab front [-4,0)
// and back [T, padend) so chunk staging never reads invalid entries.
// ---------------------------------------------------------------------------
__global__ void maskde_setup(const void* __restrict__ mask_raw, int m,
                             int* __restrict__ idx_out,
                             uint16_t* __restrict__ pair16,
                             uint32_t* __restrict__ coltab,
                             int T, int P, int padend) {
    int tid = blockIdx.x * blockDim.x + threadIdx.x;
    uint32_t sentinel = (uint32_t)P | ((uint32_t)m << 16);  // pps=1 * xls=1

    if (tid == 0) {
        const uint8_t* b8  = (const uint8_t*)mask_raw;
        const int*     b32 = (const int*)mask_raw;
        const float*   bf  = (const float*)mask_raw;
        int cnt = 0; bool ok = true;
        for (int i = 0; i < DMAX; ++i) { uint8_t v = b8[i]; if (v > 1) ok = false; cnt += (v != 0); }
        int mode;
        if (ok && cnt == m) {
            mode = 0;
        } else {
            cnt = 0; ok = true;
            for (int i = 0; i < DMAX; ++i) { int v = b32[i]; if (v != 0 && v != 1) ok = false; cnt += (v != 0); }
            mode = (ok && cnt == m) ? 1 : 2;
        }
        int k = 0;
        for (int i = 0; i < DMAX && k < m; ++i) {
            bool on = (mode == 0) ? (b8[i] != 0)
                    : (mode == 1) ? (b32[i] != 0)
                                  : (bf[i] != 0.0f);
            if (on) idx_out[k++] = i;
        }
        for (int q = -4; q < 0; ++q) coltab[q] = sentinel;   // front pad
    }

    int stride = gridDim.x * blockDim.x;
    for (int q = T + tid; q < padend; q += stride)           // back pad
        coltab[q] = sentinel;

    for (int p = tid; p < P; p += stride) {
        int rem = p, i = 0;
        while (rem >= m - i) { rem -= (m - i); ++i; }
        int j = i + rem;

        pair16[p] = (uint16_t)(i | (j << 8));

        if (p < m)
            coltab[p] = (uint32_t)P | ((uint32_t)p << 16);      // order-1
        coltab[m + p] = (uint32_t)p | ((uint32_t)m << 16);      // order-2

        int mi = m - i;
        long long Si  = ((long long)m * (m + 1) * (m + 2)
                       - (long long)mi * (mi + 1) * (mi + 2)) / 6;
        int Rij = ((m - i) + (m - j + 1)) * (j - i) / 2;
        int base = m + P + (int)Si + Rij;
        for (int k3 = j; k3 < m; ++k3)
            coltab[base + (k3 - j)] = (uint32_t)p | ((uint32_t)k3 << 16);
    }
}

// ---------------------------------------------------------------------------
// Expand: block = (column chunk, 16-row group).  Table slice + pairtab are
// staged into LDS ONCE; the steady-state loop has NO global loads (ds_read +
// aligned global_store only), so stores stream without vmcnt serialization.
// Per-(row,chunk) boundaries are shifted so every float4 store is 16B-aligned.
// ---------------------------------------------------------------------------
__global__ __launch_bounds__(BLK) void
maskde_expand(const float* __restrict__ x, const int* __restrict__ idx,
              const uint16_t* __restrict__ pair16g,
              const uint32_t* __restrict__ coltab,
              float* __restrict__ out,
              int m, int T, int P, int rows, int nchunks) {
    extern __shared__ uint8_t smraw[];
    const int tabw  = swz(CW + 8) + 1;                 // padded entries
    uint32_t* tabL  = (uint32_t*)smraw;                // tabw u32
    uint16_t* pairL = (uint16_t*)(smraw + (size_t)tabw * 4);
    float*    fbase = (float*)(smraw + (size_t)tabw * 4 + ((2 * P + 15) & ~15));
    const int XSTR  = m + 1;
    const int PPSTR = P + 1;

    const int chunk = blockIdx.x % nchunks;
    const int rowg  = blockIdx.x / nchunks;
    const int c0    = chunk * CW;
    const bool lastc = (chunk == nchunks - 1);
    const int tid  = threadIdx.x;
    const int wave = tid >> 6;
    const int lane = tid & 63;

    // stage table slice [c0-4, c0+CW+4) and pairtab into LDS
    for (int q = tid; q < CW + 8; q += BLK)
        tabL[swz(q)] = coltab[c0 - 4 + q];
    for (int p = tid; p < P; p += BLK)
        pairL[p] = pair16g[p];
    __syncthreads();

    float* xls = fbase + wave * (XSTR + PPSTR);
    float* pps = xls + XSTR;

    for (int rr = 0; rr < RPW; ++rr) {
        const int rowbase = rowg * RPB + rr * WPB;

        // cooperative gather of the round's WPB rows
        for (int w = 0; w < WPB; ++w) {
            int row = rowbase + w;
            if (row < rows) {
                float* xw = fbase + w * (XSTR + PPSTR);
                for (int k = tid; k <= m; k += BLK)
                    xw[k] = (k < m) ? x[row * DMAX + idx[k]] : 1.0f;
            }
        }
        __syncthreads();

        // cooperative pair products for the round's rows
        for (int w = 0; w < WPB; ++w) {
            int row = rowbase + w;
            if (row < rows) {
                const float* xw = fbase + w * (XSTR + PPSTR);
                float*       pw = (float*)(xw + XSTR);
                for (int p = tid; p <= P; p += BLK) {
                    float v = 1.0f;
                    if (p < P) {
                        uint32_t ij = pairL[p];
                        v = xw[ij & 0xFF] * xw[(ij >> 8) & 0xFF];
                    }
                    pw[p] = v;
                }
            }
        }
        __syncthreads();

        // per-wave streaming of its row's column chunk (no global loads)
        const int row = rowbase + wave;
        if (row < rows) {
            const long long rT = (long long)row * (long long)T;
            float* orow = out + rT;
            int a = (c0 == 0) ? 0 : c0 - (int)((rT + c0) & 3);
            int b = lastc ? T : (c0 + CW - (int)((rT + c0 + CW) & 3));
            int astart = a + (int)((4 - ((rT + a) & 3)) & 3);
            if (astart > b) astart = b;

            // prologue [a, astart)  (chunk 0 only, <=3 elems)
            if (lane < astart - a) {
                int c = a + lane;
                uint32_t e = tabL[swz(c - c0 + 4)];
                orow[c] = pps[e & 0xFFFF] * xls[e >> 16];
            }

            const int nvv = (b - astart) >> 2;
            for (int v = lane; v < nvv; v += 64) {
                int c  = astart + 4 * v;
                int ib = c - c0 + 4;
                uint32_t e0 = tabL[swz(ib)];
                uint32_t e1 = tabL[swz(ib + 1)];
                uint32_t e2 = tabL[swz(ib + 2)];
                uint32_t e3 = tabL[swz(ib + 3)];
                f32x4 o;
                o.x = pps[e0 & 0xFFFF] * xls[e0 >> 16];
                o.y = pps[e1 & 0xFFFF] * xls[e1 >> 16];
                o.z = pps[e2 & 0xFFFF] * xls[e2 >> 16];
                o.w = pps[e3 & 0xFFFF] * xls[e3 >> 16];
                *(f32x4*)(orow + c) = o;   // 16B-aligned by construction
            }

            // tail [astart+4*nvv, b)  (last chunk only, <=3 elems)
            int c = astart + 4 * nvv + lane;
            if (c < b) {
                uint32_t e = tabL[swz(c - c0 + 4)];
                orow[c] = pps[e & 0xFFFF] * xls[e >> 16];
            }
        }
        __syncthreads();
    }
}

extern "C" void kernel_launch(void* const* d_in, const int* in_sizes, int n_in,
                              void* d_out, int out_size, void* d_ws, size_t ws_size,
                              hipStream_t stream) {
    const float* x    = (const float*)d_in[0];
    const void*  mask = d_in[1];
    float*       out  = (float*)d_out;

    int rows = in_sizes[0] / DMAX;
    if (rows <= 0 || out_size <= 0) return;
    long long T = (long long)out_size / rows;

    // recover m from T(m) = m + m(m+1)/2 + m(m+1)(m+2)/6
    int m = -1;
    for (int mm = 0; mm <= DMAX; ++mm) {
        long long t = (long long)mm
                    + (long long)mm * (mm + 1) / 2
                    + (long long)mm * (mm + 1) * (mm + 2) / 6;
        if (t == T) { m = mm; break; }
    }
    if (m <= 0) return;

    int P       = m * (m + 1) / 2;
    int nchunks = (int)((T + CW - 1) / CW);
    int padend  = nchunks * CW + 4;

    int*      idx    = (int*)d_ws;                                   // 512 B
    uint16_t* pair16 = (uint16_t*)((char*)d_ws + 1024);              // 2P B
    uint32_t* coltab = (uint32_t*)((char*)d_ws + 32768) + 4;         // front pad

    int sblocks = (P + 255) / 256;
    if (sblocks < 1) sblocks = 1;
    maskde_setup<<<sblocks, 256, 0, stream>>>(mask, m, idx, pair16, coltab,
                                              (int)T, P, padend);

    int rowgroups = (rows + RPB - 1) / RPB;
    int grid = rowgroups * nchunks;

    int tabw = (CW + 8) + ((CW + 8) >> 5) + 1;
    size_t shmem = (size_t)tabw * 4 + ((2 * P + 15) & ~15)
                 + (size_t)WPB * (m + 1 + P + 1) * sizeof(float);
    maskde_expand<<<grid, BLK, shmem, stream>>>(x, idx, pair16, coltab, out,
                                                m, (int)T, P, rows, nchunks);
}

// Round 8
// 127.598 us; speedup vs baseline: 1.3467x; 1.3467x over previous
//
#include <hip/hip_runtime.h>
#include <stdint.h>

#define DMAX 80
#define BLK  256
#define XW   96          // padded row stride of xsel_all (>= m+1, <=96)
#define EPB  4096        // output elements per block (16 KB)

typedef float f32x4 __attribute__((ext_vector_type(4)));

// ---------------------------------------------------------------------------
// Setup: mask detect + compact idx; pairtab (u16 i|j<<8); coltab base copy
// plus 3 shifted copies (copy s at coltab[s*tpad + (c-s)] holds entry c) so
// a 16B-aligned uint4 load exists for any column phase.
//   column c = pps[p] * xsel[k]; entry = p | k<<16
//     [0,m)      order-1: p=P (sentinel pps=1), k=c
//     [m, m+P)   order-2: p=rank,               k=m (sentinel x=1)
//     [m+P, T)   order-3: run over k in [j,m) per pair (i,j)
// ---------------------------------------------------------------------------
__global__ void maskde_setup(const void* __restrict__ mask_raw, int m,
                             int* __restrict__ idx_out,
                             uint16_t* __restrict__ pair16,
                             uint32_t* __restrict__ coltab,
                             int tpad, int T, int P) {
    int tid = blockIdx.x * blockDim.x + threadIdx.x;

    if (tid == 0) {
        const uint8_t* b8  = (const uint8_t*)mask_raw;
        const int*     b32 = (const int*)mask_raw;
        const float*   bf  = (const float*)mask_raw;
        int cnt = 0; bool ok = true;
        for (int i = 0; i < DMAX; ++i) { uint8_t v = b8[i]; if (v > 1) ok = false; cnt += (v != 0); }
        int mode;
        if (ok && cnt == m) {
            mode = 0;
        } else {
            cnt = 0; ok = true;
            for (int i = 0; i < DMAX; ++i) { int v = b32[i]; if (v != 0 && v != 1) ok = false; cnt += (v != 0); }
            mode = (ok && cnt == m) ? 1 : 2;
        }
        int k = 0;
        for (int i = 0; i < DMAX && k < m; ++i) {
            bool on = (mode == 0) ? (b8[i] != 0)
                    : (mode == 1) ? (b32[i] != 0)
                                  : (bf[i] != 0.0f);
            if (on) idx_out[k++] = i;
        }
    }

    int stride = gridDim.x * blockDim.x;
    for (int p = tid; p < P; p += stride) {
        int rem = p, i = 0;
        while (rem >= m - i) { rem -= (m - i); ++i; }
        int j = i + rem;

        pair16[p] = (uint16_t)(i | (j << 8));

        #define WR4(c, v) do {                                              \
            int _c = (c); uint32_t _v = (v);                                \
            coltab[_c] = _v;                                                \
            if (_c >= 1) coltab[tpad     + _c - 1] = _v;                    \
            if (_c >= 2) coltab[2 * tpad + _c - 2] = _v;                    \
            if (_c >= 3) coltab[3 * tpad + _c - 3] = _v;                    \
        } while (0)

        if (p < m)
            WR4(p, (uint32_t)P | ((uint32_t)p << 16));        // order-1
        WR4(m + p, (uint32_t)p | ((uint32_t)m << 16));        // order-2

        int mi = m - i;
        long long Si  = ((long long)m * (m + 1) * (m + 2)
                       - (long long)mi * (mi + 1) * (mi + 2)) / 6;
        int Rij = ((m - i) + (m - j + 1)) * (j - i) / 2;
        int base = m + P + (int)Si + Rij;
        for (int k3 = j; k3 < m; ++k3)
            WR4(base + (k3 - j), (uint32_t)p | ((uint32_t)k3 << 16));
        #undef WR4
    }
}

// ---------------------------------------------------------------------------
// Pre-gather selected x values: xsel[row*XW + k] = x[row*80 + idx[k]] for
// k<m, 1.0 for k>=m (covers the k==m sentinel).  Tiny (3 MB write).
// ---------------------------------------------------------------------------
__global__ void maskde_xsel(const float* __restrict__ x,
                            const int* __restrict__ idx,
                            float* __restrict__ xsel, int m, int rows) {
    int g = blockIdx.x * BLK + threadIdx.x;
    int total = rows * XW;
    for (; g < total; g += gridDim.x * BLK) {
        int row = g / XW, k = g - row * XW;
        xsel[g] = (k < m) ? x[row * DMAX + idx[k]] : 1.0f;
    }
}

// ---------------------------------------------------------------------------
// Expand, FILL-SHAPED: block b writes flat elements [b*EPB, (b+1)*EPB) --
// consecutive blocks write consecutive bytes (compact device-wide write
// window, DRAM-page friendly).  A block spans <=2 rows; their pair products
// are rebuilt in LDS (no extra HBM traffic).  Main loop: aligned uint4
// table load (L2) + 8 LDS reads + aligned float4 store, 4x unrolled.
// ---------------------------------------------------------------------------
__global__ __launch_bounds__(BLK) void
maskde_expand(const float* __restrict__ xsel,
              const uint16_t* __restrict__ pair16,
              const uint32_t* __restrict__ coltab, int tpad,
              float* __restrict__ out, int m, int T, int P,
              int rows, int total) {
    extern __shared__ float sm[];
    float* xls0 = sm;            // XW
    float* xls1 = sm + XW;       // XW
    float* pps0 = sm + 2 * XW;   // P+1
    float* pps1 = pps0 + (P + 1);

    const int tid = threadIdx.x;
    const int e0  = blockIdx.x * EPB;
    const int r0  = e0 / T;
    const int r0start = r0 * T;
    const bool has1 = (r0 + 1 < rows);

    // gather both rows' pre-selected values (waves 0-1: row0, waves 2-3: row1)
    if (tid < XW) {
        xls0[tid] = xsel[r0 * XW + tid];
    } else if (tid >= 128 && tid < 128 + XW) {
        int k = tid - 128;
        xls1[k] = has1 ? xsel[(r0 + 1) * XW + k] : 1.0f;
    }
    __syncthreads();

    // pair products for both rows (+ sentinel at P)
    for (int p = tid; p <= P; p += BLK) {
        float v0 = 1.0f, v1 = 1.0f;
        if (p < P) {
            uint32_t ij = pair16[p];
            int i = ij & 0xFF, j = (ij >> 8) & 0xFF;
            v0 = xls0[i] * xls0[j];
            v1 = xls1[i] * xls1[j];
        }
        pps0[p] = v0;
        pps1[p] = v1;
    }
    __syncthreads();

#pragma unroll
    for (int it = 0; it < EPB / (4 * BLK); ++it) {
        int ee = e0 + (tid << 2) + it * (4 * BLK);
        if (ee >= total) break;
        int c = ee - r0start;
        const float* pS = pps0;
        const float* xS = xls0;
        if (c >= T) { c -= T; pS = pps1; xS = xls1; }

        if (c <= T - 4 && ee + 3 < total) {
            int s = c & 3;
            const uint4* tp = (const uint4*)(coltab + (size_t)s * tpad + (c - s));
            uint4 t = *tp;
            f32x4 o;
            o.x = pS[t.x & 0xFFFF] * xS[t.x >> 16];
            o.y = pS[t.y & 0xFFFF] * xS[t.y >> 16];
            o.z = pS[t.z & 0xFFFF] * xS[t.z >> 16];
            o.w = pS[t.w & 0xFFFF] * xS[t.w >> 16];
            *(f32x4*)(out + ee) = o;   // 16B aligned: ee % 4 == 0
        } else {
            // row-crossing quad or buffer tail: scalar
            for (int u = 0; u < 4; ++u) {
                int e2 = ee + u;
                if (e2 >= total) break;
                int c2 = e2 - r0start;
                const float* p2 = pps0;
                const float* x2 = xls0;
                if (c2 >= T) { c2 -= T; p2 = pps1; x2 = xls1; }
                uint32_t en = coltab[c2];
                out[e2] = p2[en & 0xFFFF] * x2[en >> 16];
            }
        }
    }
}

extern "C" void kernel_launch(void* const* d_in, const int* in_sizes, int n_in,
                              void* d_out, int out_size, void* d_ws, size_t ws_size,
                              hipStream_t stream) {
    const float* x    = (const float*)d_in[0];
    const void*  mask = d_in[1];
    float*       out  = (float*)d_out;

    int rows = in_sizes[0] / DMAX;
    if (rows <= 0 || out_size <= 0) return;
    long long Tll = (long long)out_size / rows;

    // recover m from T(m) = m + m(m+1)/2 + m(m+1)(m+2)/6
    int m = -1;
    for (int mm = 0; mm <= DMAX; ++mm) {
        long long t = (long long)mm
                    + (long long)mm * (mm + 1) / 2
                    + (long long)mm * (mm + 1) * (mm + 2) / 6;
        if (t == Tll) { m = mm; break; }
    }
    if (m <= 0) return;

    int T    = (int)Tll;
    int P    = m * (m + 1) / 2;
    int tpad = (T + 3) & ~3;
    int total = rows * T;

    int*      idx    = (int*)d_ws;                             // 512 B
    uint16_t* pair16 = (uint16_t*)((char*)d_ws + 1024);        // 2P B
    uint32_t* coltab = (uint32_t*)((char*)d_ws + 32768);       // 4*tpad u32
    float*    xsel   = (float*)((char*)d_ws + 32768
                                + (size_t)4 * tpad * 4 + 256); // rows*XW f32

    int sblocks = (P + 255) / 256;
    if (sblocks < 1) sblocks = 1;
    maskde_setup<<<sblocks, 256, 0, stream>>>(mask, m, idx, pair16, coltab,
                                              tpad, T, P);

    int xblocks = (rows * XW + BLK - 1) / BLK;
    if (xblocks > 2048) xblocks = 2048;
    maskde_xsel<<<xblocks, BLK, 0, stream>>>(x, idx, xsel, m, rows);

    int nb = (total + EPB - 1) / EPB;
    size_t shmem = (size_t)(2 * XW + 2 * (P + 1)) * sizeof(float);
    maskde_expand<<<nb, BLK, shmem, stream>>>(xsel, pair16, coltab, tpad,
                                              out, m, T, P, rows, total);
}